// Round 10
// baseline (806.372 us; speedup 1.0000x reference)
//
#include <hip/hip_runtime.h>
#include <hip/hip_bf16.h>
#include <hip/hip_fp8.h>

// ---------- types ----------
typedef __attribute__((ext_vector_type(4))) float  f32x4;
typedef __attribute__((ext_vector_type(8))) unsigned short u16x8;
typedef __attribute__((ext_vector_type(4))) unsigned short u16x4;
typedef long long f8x8;   // 8 fp8 in 2 VGPRs (MFMA fp8 operand)

#define DIM 384
#define NE 8
#define HID 1536
#define NB 32
#define HW 1024
#define T_TOK 32768  // NB*HW

__device__ __forceinline__ unsigned short f2bf(float f) {
    unsigned int u = __float_as_uint(f);
    u = (u + 0x7fffu + ((u >> 16) & 1u)) >> 16;
    return (unsigned short)u;
}
__device__ __forceinline__ float bf2f(unsigned short u) {
    return __uint_as_float((unsigned int)u << 16);
}
__device__ __forceinline__ unsigned char f2fp8(float f) {
    __hip_fp8_e4m3 h(f);
    return (unsigned char)h.__x;
}
__device__ __forceinline__ float gelu_f(float v) {
    float zz = v * fmaf(v * v, -0.07135481627f, -1.5957691216f); // = -2z
    return v * __builtin_amdgcn_rcpf(1.f + __expf(zz));
}

// ---------- K0a: transpose fp32 [E][R][C] -> fp8 [E][C][R]  (used for W1) ----------
__global__ __launch_bounds__(256) void k_transpose8(const float* __restrict__ src,
                                                    unsigned char* __restrict__ dst,
                                                    int R, int C) {
    int b = blockIdx.x;
    int ctiles = C >> 5;
    int rtiles = R >> 5;
    int ct = b % ctiles;
    int rt = (b / ctiles) % rtiles;
    int e  = b / (ctiles * rtiles);
    __shared__ float t[32][33];
    int tid = threadIdx.x;
    const float* s = src + (size_t)e * R * C;
    unsigned char* d = dst + (size_t)e * C * R;
#pragma unroll
    for (int k = 0; k < 4; ++k) {
        int idx = k * 256 + tid;
        int rr = idx >> 5, cc = idx & 31;
        t[rr][cc] = s[(size_t)(rt * 32 + rr) * C + ct * 32 + cc];
    }
    __syncthreads();
    int cc = tid >> 3, r4 = tid & 7;
    unsigned int pk = 0;
#pragma unroll
    for (int i = 0; i < 4; ++i)
        pk |= (unsigned int)f2fp8(t[r4 * 4 + i][cc]) << (8 * i);
    *(unsigned int*)&d[(size_t)(ct * 32 + cc) * R + rt * 32 + r4 * 4] = pk;
}

// ---------- K0b: W2 [E][HID][DIM] fp32 -> fp8 [E][chunk48][DIM][32] with baked
//            k-slot permutation p(h) = 8*((h&15)>>2) + 4*(h>>4) + (h&3)  ----------
__global__ __launch_bounds__(256) void k_transw2(const float* __restrict__ src,
                                                 unsigned char* __restrict__ dst) {
    int b = blockIdx.x;
    int ct = b % 12;            // dim tile (32)
    int rt = (b / 12) % 48;     // hid chunk (32)
    int e  = b / (12 * 48);
    __shared__ float t[32][33];
    int tid = threadIdx.x;
    const float* s = src + (size_t)e * HID * DIM;
#pragma unroll
    for (int k = 0; k < 4; ++k) {
        int idx = k * 256 + tid;
        int rr = idx >> 5, cc = idx & 31;
        t[rr][cc] = s[(size_t)(rt * 32 + rr) * DIM + ct * 32 + cc];
    }
    __syncthreads();
    int cc = tid >> 3, r4 = tid & 7;       // cc: dim-in-tile, r4: hid quad (h = 4*r4+i)
    unsigned int pk = 0;
#pragma unroll
    for (int i = 0; i < 4; ++i)
        pk |= (unsigned int)f2fp8(t[r4 * 4 + i][cc]) << (8 * i);
    // position of h=4*r4+i is 8*(r4&3) + 4*(r4>>2) + i  (4 consecutive -> one u32)
    size_t off = (((size_t)e * 48 + rt) * DIM + ct * 32 + cc) * 32 + 8 * (r4 & 3) + 4 * (r4 >> 2);
    *(unsigned int*)&dst[off] = pk;
}

// ---------- K1: depthwise 7x7 conv, NCHW -> NCHW (xconv) ----------
__global__ __launch_bounds__(256) void k_conv(const float* __restrict__ in,
                                              const float* __restrict__ dw_w,
                                              const float* __restrict__ dw_b,
                                              float* __restrict__ xconv) {
    int nc = blockIdx.x;             // n*384 + c
    int c = nc % DIM;
    __shared__ float tile[38 * 38];
    __shared__ float wt[49];
    const float* plane = in + (size_t)nc * HW;
    int tid = threadIdx.x;
    if (tid < 49) wt[tid] = dw_w[c * 49 + tid];
    for (int idx = tid; idx < 38 * 38; idx += 256) {
        int ty = idx / 38, tx = idx % 38;
        int ih = ty - 3, iw = tx - 3;
        float v = 0.f;
        if ((unsigned)ih < 32u && (unsigned)iw < 32u) v = plane[ih * 32 + iw];
        tile[idx] = v;
    }
    __syncthreads();
    float bias = dw_b[c];
    int w = tid & 31, h0 = (tid >> 5) << 2;   // 4 consecutive h rows per thread
    float acc[4] = {bias, bias, bias, bias};
#pragma unroll
    for (int iy = 0; iy < 10; ++iy) {
        float r[7];
#pragma unroll
        for (int dx = 0; dx < 7; ++dx) r[dx] = tile[(h0 + iy) * 38 + w + dx];
#pragma unroll
        for (int o = 0; o < 4; ++o) {
            int dy = iy - o;
            if (dy >= 0 && dy < 7) {
                float a = 0.f;
#pragma unroll
                for (int dx = 0; dx < 7; ++dx) a += r[dx] * wt[dy * 7 + dx];
                acc[o] += a;
            }
        }
    }
    float* outp = xconv + (size_t)nc * HW;
#pragma unroll
    for (int o = 0; o < 4; ++o) outp[(h0 + o) * 32 + w] = acc[o];
}

// ---------- K2: LayerNorm + gate + top-2 routing (fp8 X out) ----------
__global__ __launch_bounds__(256) void k_ln_gate(const float* __restrict__ xconv,
                                                 const float* __restrict__ ln_g,
                                                 const float* __restrict__ ln_b,
                                                 const float* __restrict__ gate_w,
                                                 unsigned char* __restrict__ lnout,
                                                 int* __restrict__ lists,
                                                 float* __restrict__ wgts,
                                                 int* __restrict__ counts) {
    __shared__ float xs[32][385];
    __shared__ float gw[8][384];
    __shared__ float gls[384], bls[384];
    __shared__ int hcnt[8], hbase[8];
    __shared__ int lexp[32][2];
    __shared__ int lpos[32][2];
    __shared__ float lw[32][2];

    int b = blockIdx.x;
    int n = b >> 5;
    int hw0 = (b & 31) << 5;
    int tid = threadIdx.x;

    for (int i = tid; i < 384; i += 256) { gls[i] = ln_g[i]; bls[i] = ln_b[i]; }
    for (int i = tid; i < 8 * 384; i += 256) gw[i / 384][i % 384] = gate_w[i];
    if (tid < 8) hcnt[tid] = 0;

    const float* base = xconv + (size_t)n * DIM * HW + hw0;
#pragma unroll
    for (int k = 0; k < 48; ++k) {
        int idx = k * 256 + tid;
        int c = idx >> 5, j = idx & 31;
        xs[j][c] = base[(size_t)c * HW + j];
    }
    __syncthreads();

    int tok = tid >> 3, jj = tid & 7;     // 8 lanes per token
    float sum = 0.f, sq = 0.f;
#pragma unroll
    for (int k = 0; k < 48; ++k) {
        float v = xs[tok][jj + 8 * k];
        sum += v; sq += v * v;
    }
#pragma unroll
    for (int m = 1; m < 8; m <<= 1) { sum += __shfl_xor(sum, m); sq += __shfl_xor(sq, m); }
    float mu = sum * (1.f / 384.f);
    float var = sq * (1.f / 384.f) - mu * mu;
    float rstd = rsqrtf(var + 1e-6f);

    int tglob = n * HW + hw0 + tok;
    float p[8] = {0, 0, 0, 0, 0, 0, 0, 0};
#pragma unroll
    for (int k = 0; k < 48; ++k) {
        int c = jj + 8 * k;
        float v = (xs[tok][c] - mu) * rstd * gls[c] + bls[c];
        lnout[(size_t)tglob * DIM + c] = f2fp8(v);
#pragma unroll
        for (int e = 0; e < 8; ++e) p[e] += v * gw[e][c];
    }
#pragma unroll
    for (int e = 0; e < 8; ++e)
#pragma unroll
        for (int m = 1; m < 8; m <<= 1) p[e] += __shfl_xor(p[e], m);

    if (jj == 0) {
        int i0 = 0; float v0 = p[0];
#pragma unroll
        for (int e = 1; e < 8; ++e) if (p[e] > v0) { v0 = p[e]; i0 = e; }
        int i1 = -1; float v1 = -1e30f;
#pragma unroll
        for (int e = 0; e < 8; ++e) if (e != i0 && p[e] > v1) { v1 = p[e]; i1 = e; }
        float w0 = 1.f / (1.f + __expf(v1 - v0));
        float w1 = 1.f - w0;
        lexp[tok][0] = i0; lexp[tok][1] = i1;
        lw[tok][0] = w0;  lw[tok][1] = w1;
        lpos[tok][0] = atomicAdd(&hcnt[i0], 1);
        lpos[tok][1] = atomicAdd(&hcnt[i1], 1);
    }
    __syncthreads();
    if (tid < 8) hbase[tid] = atomicAdd(&counts[tid], hcnt[tid]);
    __syncthreads();
    if (jj == 0) {
#pragma unroll
        for (int s = 0; s < 2; ++s) {
            int e = lexp[tok][s];
            int pos = hbase[e] + lpos[tok][s];
            lists[e * T_TOK + pos] = (tglob << 1) | s;
            wgts[e * T_TOK + pos] = lw[tok][s];
        }
    }
}

// ---------- K3: gathered expert MLP — barrier-free, LDS-free register fusion ----------
// v10: each WAVE owns 32 token-slots end-to-end. X B-frags live in registers
//      (loaded once). Per 32-hid chunk: GEMM1 (W1 A-frags from L2) -> gelu+fp8
//      pack in regs -> H IS the GEMM2 B-frag directly (k-slot permutation baked
//      into w2p layout) -> GEMM2 accumulates Yacc. No LDS, no barriers, no
//      inter-wave dependency. 1 wave/SIMD, 512-reg budget.
__global__ __launch_bounds__(256, 1) void k_moe(const unsigned char* __restrict__ ln,
                                                const unsigned char* __restrict__ w1t, // [8][1536][384] fp8
                                                const unsigned char* __restrict__ w2p, // [8][48][384][32] fp8 (perm)
                                                const float* __restrict__ b1,
                                                const float* __restrict__ b2,
                                                const int* __restrict__ lists,
                                                const float* __restrict__ wgts,
                                                const int* __restrict__ counts,
                                                unsigned short* __restrict__ y0,
                                                unsigned short* __restrict__ y1) {
    int e    = blockIdx.x & 7;        // expert -> fixed XCD (round-robin dispatch)
    int tile = blockIdx.x >> 3;       // 0..511 ; block covers 128 entries
    int cnt = counts[e];
    if (tile * 128 >= cnt) return;

    int tid = threadIdx.x;
    int wid = tid >> 6;               // wave: 32 entries
    int l   = tid & 63;
    int lr  = l & 15;                 // frag row/col index
    int lq  = l >> 4;                 // k-group

    int base = tile * 128 + wid * 32;
    int idx0 = base + lr;             // token-tile 0
    int idx1 = idx0 + 16;             // token-tile 1
    int ent0 = (idx0 < cnt) ? lists[e * T_TOK + idx0] : -1;
    int ent1 = (idx1 < cnt) ? lists[e * T_TOK + idx1] : -1;
    float wv0 = (idx0 < cnt) ? wgts[e * T_TOK + idx0] : 0.f;
    float wv1 = (idx1 < cnt) ? wgts[e * T_TOK + idx1] : 0.f;
    int tok0 = (ent0 < 0) ? 0 : (ent0 >> 1);
    int tok1 = (ent1 < 0) ? 0 : (ent1 >> 1);

    // ---- X B-frags: lane (lr,lq) holds X[tok[lr]][ks*32 + lq*8 .. +8), ks=0..11
    f8x8 xf0[12], xf1[12];
    {
        const unsigned char* px0 = ln + (size_t)tok0 * DIM + lq * 8;
        const unsigned char* px1 = ln + (size_t)tok1 * DIM + lq * 8;
#pragma unroll
        for (int ks = 0; ks < 12; ++ks) {
            xf0[ks] = *(const f8x8*)(px0 + ks * 32);
            xf1[ks] = *(const f8x8*)(px1 + ks * 32);
        }
    }

    // W1 A-frag row pointers (bumped by 32*DIM per chunk)
    const unsigned char* pa0 = w1t + ((size_t)e * HID + lr) * DIM + lq * 8;
    const unsigned char* pa1 = pa0 + (size_t)16 * DIM;
    // W2 perm-layout pointer: [e][c][dim][32]; loads at nj*512 imm (bumped by 384*32)
    const unsigned char* pv = w2p + (((size_t)e * 48) * DIM + lr) * 32 + lq * 8;
    // b1 pointer (bumped by 32 floats per chunk)
    const float* pb1 = b1 + e * HID + lq * 4;

    f32x4 Yacc[24][2] = {};   // [dim-tile nj][token-tile t]; lane: dim=nj*16+lq*4+i, tok=t*16+lr

#pragma unroll 2
    for (int c = 0; c < 48; ++c) {
        // ---- stream W1 frags (2 hid-tiles x 12 ks) and W2 frags (24 dim-tiles)
        f8x8 wa0[12], wa1[12];
#pragma unroll
        for (int ks = 0; ks < 12; ++ks) {
            wa0[ks] = *(const f8x8*)(pa0 + ks * 32);
            wa1[ks] = *(const f8x8*)(pa1 + ks * 32);
        }
        f8x8 va[24];
#pragma unroll
        for (int nj = 0; nj < 24; ++nj)
            va[nj] = *(const f8x8*)(pv + nj * 512);
        // ---- GEMM1: H chunk (32 hid x 32 tok), bias-init
        f32x4 bv0 = *(const f32x4*)(pb1);        // hid c*32 + lq*4 + i
        f32x4 bv1 = *(const f32x4*)(pb1 + 16);   // hid c*32 + 16 + lq*4 + i
        f32x4 H00 = bv0, H01 = bv0, H10 = bv1, H11 = bv1;  // [hidtile][toktile]
#pragma unroll
        for (int ks = 0; ks < 12; ++ks) {
            H00 = __builtin_amdgcn_mfma_f32_16x16x32_fp8_fp8(wa0[ks], xf0[ks], H00, 0, 0, 0);
            H01 = __builtin_amdgcn_mfma_f32_16x16x32_fp8_fp8(wa0[ks], xf1[ks], H01, 0, 0, 0);
            H10 = __builtin_amdgcn_mfma_f32_16x16x32_fp8_fp8(wa1[ks], xf0[ks], H10, 0, 0, 0);
            H11 = __builtin_amdgcn_mfma_f32_16x16x32_fp8_fp8(wa1[ks], xf1[ks], H11, 0, 0, 0);
        }
        // ---- gelu + fp8 pack: lane(lr,lq) holds hid {c*32+lq*4+i} (lo) and
        //      {c*32+16+lq*4+i} (hi) for token col lr -> B-frag = {lo, hi} as-is.
        unsigned int lo0 = 0, hi0 = 0, lo1 = 0, hi1 = 0;
#pragma unroll
        for (int i = 0; i < 4; ++i) {
            lo0 |= (unsigned int)f2fp8(gelu_f(H00[i])) << (8 * i);
            hi0 |= (unsigned int)f2fp8(gelu_f(H10[i])) << (8 * i);
            lo1 |= (unsigned int)f2fp8(gelu_f(H01[i])) << (8 * i);
            hi1 |= (unsigned int)f2fp8(gelu_f(H11[i])) << (8 * i);
        }
        f8x8 bf0 = (f8x8)((((unsigned long long)hi0) << 32) | lo0);
        f8x8 bf1 = (f8x8)((((unsigned long long)hi1) << 32) | lo1);
        // ---- GEMM2: Yacc[nj][t] += W2(dim,K=32-chunk) x H
#pragma unroll
        for (int nj = 0; nj < 24; ++nj) {
            Yacc[nj][0] = __builtin_amdgcn_mfma_f32_16x16x32_fp8_fp8(va[nj], bf0, Yacc[nj][0], 0, 0, 0);
            Yacc[nj][1] = __builtin_amdgcn_mfma_f32_16x16x32_fp8_fp8(va[nj], bf1, Yacc[nj][1], 0, 0, 0);
        }
        // ---- bump pointers
        pa0 += (size_t)32 * DIM;
        pa1 += (size_t)32 * DIM;
        pv  += (size_t)DIM * 32;
        pb1 += 32;
    }

    // ---- epilogue: lane holds token t*16+lr (col), dims nj*16+lq*4+i (rows)
#pragma unroll
    for (int t = 0; t < 2; ++t) {
        int ent = t ? ent1 : ent0;
        if (ent < 0) continue;
        float wv = t ? wv1 : wv0;
        int tok = ent >> 1;
        unsigned short* yb = (ent & 1) ? y1 : y0;
#pragma unroll
        for (int nj = 0; nj < 24; ++nj) {
            f32x4 b2v = *(const f32x4*)&b2[e * DIM + nj * 16 + lq * 4];
            u16x4 pk;
#pragma unroll
            for (int i = 0; i < 4; ++i)
                pk[i] = f2bf((Yacc[nj][t][i] + b2v[i]) * wv);
            *(u16x4*)(yb + (size_t)tok * DIM + nj * 16 + lq * 4) = pk;
        }
    }
}

// ---------- K4: out = input + layer_scale[c] * (y0 + y1), NHWC->NCHW ----------
__global__ __launch_bounds__(256) void k_final(const float* __restrict__ input,
                                               const float* __restrict__ ls,
                                               const unsigned short* __restrict__ y0,
                                               const unsigned short* __restrict__ y1,
                                               float* __restrict__ out) {
    int b = blockIdx.x;
    int ct = b % 12;
    int hwt = (b / 12) % 32;
    int n = b / (12 * 32);
    int c0 = ct * 32, hw0 = hwt * 32;
    __shared__ float t[32][33];
    int tid = threadIdx.x;
    int t0 = n * HW + hw0;
#pragma unroll
    for (int k = 0; k < 2; ++k) {
        int idx = k * 256 + tid;
        int tl = idx >> 4, pr = idx & 15;       // 32 tokens x 16 col-pairs
        size_t o = (size_t)(t0 + tl) * DIM + c0 + pr * 2;
        unsigned int a = *(const unsigned int*)(y0 + o);
        unsigned int c = *(const unsigned int*)(y1 + o);
        t[tl][pr * 2]     = bf2f((unsigned short)a) + bf2f((unsigned short)c);
        t[tl][pr * 2 + 1] = bf2f((unsigned short)(a >> 16)) + bf2f((unsigned short)(c >> 16));
    }
    __syncthreads();
#pragma unroll
    for (int k = 0; k < 4; ++k) {
        int idx = k * 256 + tid;
        int cl = idx >> 5, j = idx & 31;
        size_t o = ((size_t)n * DIM + c0 + cl) * HW + hw0 + j;
        out[o] = input[o] + ls[c0 + cl] * t[j][cl];
    }
}

// ---------- launch ----------
extern "C" void kernel_launch(void* const* d_in, const int* in_sizes, int n_in,
                              void* d_out, int out_size, void* d_ws, size_t ws_size,
                              hipStream_t stream) {
    const float* input  = (const float*)d_in[0];
    const float* dw_w   = (const float*)d_in[1];
    const float* dw_b   = (const float*)d_in[2];
    const float* ln_g   = (const float*)d_in[3];
    const float* ln_b   = (const float*)d_in[4];
    const float* gate_w = (const float*)d_in[5];
    const float* w1     = (const float*)d_in[6];
    const float* b1     = (const float*)d_in[7];
    const float* w2     = (const float*)d_in[8];
    const float* b2     = (const float*)d_in[9];
    const float* lscale = (const float*)d_in[10];

    // ws layout (bytes)
    const size_t SZ_PLANE = (size_t)NB * DIM * HW * 4;      // 50,331,648 (xconv fp32)
    const size_t SZ_YBF   = (size_t)T_TOK * DIM * 2;        // 25,165,824 (y bf16)
    const size_t SZ_LNB   = (size_t)T_TOK * DIM;            // 12,582,912 (X fp8)
    const size_t SZ_W1    = (size_t)NE * DIM * HID;         //  4,718,592 (fp8)
    char* ws = (char*)d_ws;
    float* xconv = (float*)(ws + 0);                        // dead after k_ln_gate
    unsigned short* y0 = (unsigned short*)(ws + 0);         // overlays xconv
    unsigned short* y1 = (unsigned short*)(ws + SZ_YBF);    // still inside xconv region
    unsigned char* lnb = (unsigned char*)(ws + SZ_PLANE);
    unsigned char* w1t = (unsigned char*)(ws + SZ_PLANE + SZ_LNB);
    unsigned char* w2p = (unsigned char*)(ws + SZ_PLANE + SZ_LNB + SZ_W1);
    int*   lists  = (int*)(ws + SZ_PLANE + SZ_LNB + 2 * SZ_W1);
    float* wgt    = (float*)(ws + SZ_PLANE + SZ_LNB + 2 * SZ_W1 + 1048576);
    int*   counts = (int*)(ws + SZ_PLANE + SZ_LNB + 2 * SZ_W1 + 2 * 1048576);
    const size_t needed = SZ_PLANE + SZ_LNB + 2 * SZ_W1 + 2 * 1048576 + 256;
    if (ws_size < needed) return;

    hipMemsetAsync(counts, 0, 32, stream);
    k_transpose8<<<8 * 12 * 48, 256, 0, stream>>>(w1, w1t, DIM, HID);
    k_transw2<<<8 * 48 * 12, 256, 0, stream>>>(w2, w2p);
    k_conv<<<NB * DIM, 256, 0, stream>>>(input, dw_w, dw_b, xconv);
    k_ln_gate<<<T_TOK / 32, 256, 0, stream>>>(xconv, ln_g, ln_b, gate_w, lnb, lists, wgt, counts);
    k_moe<<<NE * 512, 256, 0, stream>>>(lnb, w1t, w2p, b1, b2, lists, wgt, counts, y0, y1);
    k_final<<<NB * 32 * 12, 256, 0, stream>>>(input, lscale, y0, y1, (float*)d_out);
}

// Round 11
// 542.331 us; speedup vs baseline: 1.4869x; 1.4869x over previous
//
#include <hip/hip_runtime.h>
#include <hip/hip_bf16.h>
#include <hip/hip_fp8.h>

// ---------- types ----------
typedef __attribute__((ext_vector_type(4))) float  f32x4;
typedef __attribute__((ext_vector_type(8))) unsigned short u16x8;
typedef __attribute__((ext_vector_type(4))) unsigned short u16x4;
typedef long long f8x8;   // 8 fp8 in 2 VGPRs (MFMA fp8 operand)

#define DIM 384
#define NE 8
#define HID 1536
#define NB 32
#define HW 1024
#define T_TOK 32768  // NB*HW

__device__ __forceinline__ unsigned short f2bf(float f) {
    unsigned int u = __float_as_uint(f);
    u = (u + 0x7fffu + ((u >> 16) & 1u)) >> 16;
    return (unsigned short)u;
}
__device__ __forceinline__ float bf2f(unsigned short u) {
    return __uint_as_float((unsigned int)u << 16);
}
__device__ __forceinline__ unsigned char f2fp8(float f) {
    __hip_fp8_e4m3 h(f);
    return (unsigned char)h.__x;
}
__device__ __forceinline__ float gelu_f(float v) {
    float zz = v * fmaf(v * v, -0.07135481627f, -1.5957691216f); // = -2z
    return v * __builtin_amdgcn_rcpf(1.f + __expf(zz));
}
__device__ __forceinline__ unsigned int pk4_fp8(float a, float b, float c, float d) {
#if __has_builtin(__builtin_amdgcn_cvt_pk_fp8_f32)
    int v = __builtin_amdgcn_cvt_pk_fp8_f32(a, b, 0, false);
    v = __builtin_amdgcn_cvt_pk_fp8_f32(c, d, v, true);
    return (unsigned int)v;
#else
    return (unsigned int)f2fp8(a) | ((unsigned int)f2fp8(b) << 8) |
           ((unsigned int)f2fp8(c) << 16) | ((unsigned int)f2fp8(d) << 24);
#endif
}

// ---------- K0: transpose fp32 [E][R][C] -> fp8 [E][C][R] ----------
__global__ __launch_bounds__(256) void k_transpose8(const float* __restrict__ src,
                                                    unsigned char* __restrict__ dst,
                                                    int R, int C) {
    int b = blockIdx.x;
    int ctiles = C >> 5;
    int rtiles = R >> 5;
    int ct = b % ctiles;
    int rt = (b / ctiles) % rtiles;
    int e  = b / (ctiles * rtiles);
    __shared__ float t[32][33];
    int tid = threadIdx.x;
    const float* s = src + (size_t)e * R * C;
    unsigned char* d = dst + (size_t)e * C * R;
#pragma unroll
    for (int k = 0; k < 4; ++k) {
        int idx = k * 256 + tid;
        int rr = idx >> 5, cc = idx & 31;
        t[rr][cc] = s[(size_t)(rt * 32 + rr) * C + ct * 32 + cc];
    }
    __syncthreads();
    int cc = tid >> 3, r4 = tid & 7;
    unsigned int pk = pk4_fp8(t[r4 * 4 + 0][cc], t[r4 * 4 + 1][cc],
                              t[r4 * 4 + 2][cc], t[r4 * 4 + 3][cc]);
    *(unsigned int*)&d[(size_t)(ct * 32 + cc) * R + rt * 32 + r4 * 4] = pk;
}

// ---------- K1: depthwise 7x7 conv, NCHW -> NCHW (xconv) ----------
__global__ __launch_bounds__(256) void k_conv(const float* __restrict__ in,
                                              const float* __restrict__ dw_w,
                                              const float* __restrict__ dw_b,
                                              float* __restrict__ xconv) {
    int nc = blockIdx.x;             // n*384 + c
    int c = nc % DIM;
    __shared__ float tile[38 * 38];
    __shared__ float wt[49];
    const float* plane = in + (size_t)nc * HW;
    int tid = threadIdx.x;
    if (tid < 49) wt[tid] = dw_w[c * 49 + tid];
    for (int idx = tid; idx < 38 * 38; idx += 256) {
        int ty = idx / 38, tx = idx % 38;
        int ih = ty - 3, iw = tx - 3;
        float v = 0.f;
        if ((unsigned)ih < 32u && (unsigned)iw < 32u) v = plane[ih * 32 + iw];
        tile[idx] = v;
    }
    __syncthreads();
    float bias = dw_b[c];
    int w = tid & 31, h0 = (tid >> 5) << 2;   // 4 consecutive h rows per thread
    float acc[4] = {bias, bias, bias, bias};
#pragma unroll
    for (int iy = 0; iy < 10; ++iy) {
        float r[7];
#pragma unroll
        for (int dx = 0; dx < 7; ++dx) r[dx] = tile[(h0 + iy) * 38 + w + dx];
#pragma unroll
        for (int o = 0; o < 4; ++o) {
            int dy = iy - o;
            if (dy >= 0 && dy < 7) {
                float a = 0.f;
#pragma unroll
                for (int dx = 0; dx < 7; ++dx) a += r[dx] * wt[dy * 7 + dx];
                acc[o] += a;
            }
        }
    }
    float* outp = xconv + (size_t)nc * HW;
#pragma unroll
    for (int o = 0; o < 4; ++o) outp[(h0 + o) * 32 + w] = acc[o];
}

// ---------- K2: LayerNorm + gate + top-2 routing (fp8 X out) ----------
__global__ __launch_bounds__(256) void k_ln_gate(const float* __restrict__ xconv,
                                                 const float* __restrict__ ln_g,
                                                 const float* __restrict__ ln_b,
                                                 const float* __restrict__ gate_w,
                                                 unsigned char* __restrict__ lnout,
                                                 int* __restrict__ lists,
                                                 float* __restrict__ wgts,
                                                 int* __restrict__ counts) {
    __shared__ float xs[32][385];
    __shared__ float gw[8][384];
    __shared__ float gls[384], bls[384];
    __shared__ int hcnt[8], hbase[8];
    __shared__ int lexp[32][2];
    __shared__ int lpos[32][2];
    __shared__ float lw[32][2];

    int b = blockIdx.x;
    int n = b >> 5;
    int hw0 = (b & 31) << 5;
    int tid = threadIdx.x;

    for (int i = tid; i < 384; i += 256) { gls[i] = ln_g[i]; bls[i] = ln_b[i]; }
    for (int i = tid; i < 8 * 384; i += 256) gw[i / 384][i % 384] = gate_w[i];
    if (tid < 8) hcnt[tid] = 0;

    const float* base = xconv + (size_t)n * DIM * HW + hw0;
#pragma unroll
    for (int k = 0; k < 48; ++k) {
        int idx = k * 256 + tid;
        int c = idx >> 5, j = idx & 31;
        xs[j][c] = base[(size_t)c * HW + j];
    }
    __syncthreads();

    int tok = tid >> 3, jj = tid & 7;     // 8 lanes per token
    float sum = 0.f, sq = 0.f;
#pragma unroll
    for (int k = 0; k < 48; ++k) {
        float v = xs[tok][jj + 8 * k];
        sum += v; sq += v * v;
    }
#pragma unroll
    for (int m = 1; m < 8; m <<= 1) { sum += __shfl_xor(sum, m); sq += __shfl_xor(sq, m); }
    float mu = sum * (1.f / 384.f);
    float var = sq * (1.f / 384.f) - mu * mu;
    float rstd = rsqrtf(var + 1e-6f);

    int tglob = n * HW + hw0 + tok;
    float p[8] = {0, 0, 0, 0, 0, 0, 0, 0};
#pragma unroll
    for (int k = 0; k < 48; ++k) {
        int c = jj + 8 * k;
        float v = (xs[tok][c] - mu) * rstd * gls[c] + bls[c];
        lnout[(size_t)tglob * DIM + c] = f2fp8(v);
#pragma unroll
        for (int e = 0; e < 8; ++e) p[e] += v * gw[e][c];
    }
#pragma unroll
    for (int e = 0; e < 8; ++e)
#pragma unroll
        for (int m = 1; m < 8; m <<= 1) p[e] += __shfl_xor(p[e], m);

    if (jj == 0) {
        int i0 = 0; float v0 = p[0];
#pragma unroll
        for (int e = 1; e < 8; ++e) if (p[e] > v0) { v0 = p[e]; i0 = e; }
        int i1 = -1; float v1 = -1e30f;
#pragma unroll
        for (int e = 0; e < 8; ++e) if (e != i0 && p[e] > v1) { v1 = p[e]; i1 = e; }
        float w0 = 1.f / (1.f + __expf(v1 - v0));
        float w1 = 1.f - w0;
        lexp[tok][0] = i0; lexp[tok][1] = i1;
        lw[tok][0] = w0;  lw[tok][1] = w1;
        lpos[tok][0] = atomicAdd(&hcnt[i0], 1);
        lpos[tok][1] = atomicAdd(&hcnt[i1], 1);
    }
    __syncthreads();
    if (tid < 8) hbase[tid] = atomicAdd(&counts[tid], hcnt[tid]);
    __syncthreads();
    if (jj == 0) {
#pragma unroll
        for (int s = 0; s < 2; ++s) {
            int e = lexp[tok][s];
            int pos = hbase[e] + lpos[tok][s];
            lists[e * T_TOK + pos] = (tglob << 1) | s;
            wgts[e * T_TOK + pos] = lw[tok][s];
        }
    }
}

// ---------- K3: gathered expert MLP, fp8 16x16x32, 4-phase hid-chunk=384 ----------
// v11: BM=64, 4 waves. Re-tiled from 12 phases of 128-hid to 4 phases of 384-hid:
//      GEMM2 K-chunk=384 (reads/MFMA 0.33->0.17), GEMM1 in 3 sub-chunks of 32 hid
//      (Hacc 32 VGPR). 8 barriers total (was 24), ~3k-cyc MFMA runs between them.
//      HW v_cvt_pk_fp8_f32 for gelu pack. 2 blocks/CU.
__global__ __launch_bounds__(256, 2) void k_moe(const unsigned char* __restrict__ ln,
                                                const unsigned char* __restrict__ w1t, // [8][1536][384] fp8
                                                const unsigned char* __restrict__ w2t, // [8][384][1536] fp8
                                                const float* __restrict__ b1,
                                                const float* __restrict__ b2,
                                                const int* __restrict__ lists,
                                                const float* __restrict__ wgts,
                                                const int* __restrict__ counts,
                                                unsigned short* __restrict__ y0,
                                                unsigned short* __restrict__ y1) {
    int e    = blockIdx.x & 7;        // expert -> fixed XCD (round-robin dispatch)
    int tile = blockIdx.x >> 3;       // 0..511
    int cnt = counts[e];
    if (tile * 64 >= cnt) return;

    __shared__ unsigned char X[64][400];     // 25,600 B
    __shared__ unsigned char Hs[64][392];    // 25,088 B (hid-chunk 384 fp8 + pad)
    __shared__ int   ents[64];
    __shared__ float wrow[64];

    int tid = threadIdx.x;
    if (tid < 64) {
        int idx = tile * 64 + tid;
        if (idx < cnt) { ents[tid] = lists[e * T_TOK + idx]; wrow[tid] = wgts[e * T_TOK + idx]; }
        else           { ents[tid] = -1;                     wrow[tid] = 0.f; }
    }
    __syncthreads();

    // gather X rows (fp8, 384B/row, 4 lanes x 6 x 16B), non-temporal
    {
        int row = tid >> 2, q = tid & 3;
        int ent = ents[row];
        int tok = (ent < 0) ? 0 : (ent >> 1);
        const u16x8* src = (const u16x8*)(ln + (size_t)tok * DIM);
#pragma unroll
        for (int r = 0; r < 6; ++r)
            *(u16x8*)&X[row][(q + r * 4) * 16] = __builtin_nontemporal_load(&src[q + r * 4]);
    }
    __syncthreads();

    int w    = tid >> 6;         // wave 0..3
    int lane = tid & 63;
    int lr = lane & 15;          // A row (hid/dim) ; B col (token)
    int lq = lane >> 4;          // 0..3 (k-group of 8 fp8)

    f32x4 Yacc[6][4] = {};   // [nj][m] : dims w*96+nj*16+lq*4+r, token m*16+lr

    for (int hc = 0; hc < 4; ++hc) {
        // ================= GEMM1: H[hc*384 .. +384) ; this wave: 96 hid rows =====
        __builtin_amdgcn_s_setprio(1);
#pragma unroll
        for (int s = 0; s < 3; ++s) {
            int hb = hc * 384 + w * 96 + s * 32;   // 32-hid group base
            const unsigned char* pa = w1t + ((size_t)e * HID + hb + lr) * DIM + lq * 8;
            f8x8 wa[2][12];
#pragma unroll
            for (int nj = 0; nj < 2; ++nj)
#pragma unroll
                for (int k = 0; k < 12; ++k)
                    wa[nj][k] = *(const f8x8*)(pa + (size_t)nj * 16 * DIM + k * 32);
            f32x4 bv0 = *(const f32x4*)&b1[e * HID + hb + lq * 4];
            f32x4 bv1 = *(const f32x4*)&b1[e * HID + hb + 16 + lq * 4];
            f32x4 Hacc[2][4];
#pragma unroll
            for (int m = 0; m < 4; ++m) { Hacc[0][m] = bv0; Hacc[1][m] = bv1; }
#pragma unroll
            for (int k = 0; k < 12; ++k) {
                f8x8 a0 = *(const f8x8*)&X[ 0 + lr][k * 32 + lq * 8];
                f8x8 a1 = *(const f8x8*)&X[16 + lr][k * 32 + lq * 8];
                f8x8 a2 = *(const f8x8*)&X[32 + lr][k * 32 + lq * 8];
                f8x8 a3 = *(const f8x8*)&X[48 + lr][k * 32 + lq * 8];
                Hacc[0][0] = __builtin_amdgcn_mfma_f32_16x16x32_fp8_fp8(wa[0][k], a0, Hacc[0][0], 0, 0, 0);
                Hacc[0][1] = __builtin_amdgcn_mfma_f32_16x16x32_fp8_fp8(wa[0][k], a1, Hacc[0][1], 0, 0, 0);
                Hacc[0][2] = __builtin_amdgcn_mfma_f32_16x16x32_fp8_fp8(wa[0][k], a2, Hacc[0][2], 0, 0, 0);
                Hacc[0][3] = __builtin_amdgcn_mfma_f32_16x16x32_fp8_fp8(wa[0][k], a3, Hacc[0][3], 0, 0, 0);
                Hacc[1][0] = __builtin_amdgcn_mfma_f32_16x16x32_fp8_fp8(wa[1][k], a0, Hacc[1][0], 0, 0, 0);
                Hacc[1][1] = __builtin_amdgcn_mfma_f32_16x16x32_fp8_fp8(wa[1][k], a1, Hacc[1][1], 0, 0, 0);
                Hacc[1][2] = __builtin_amdgcn_mfma_f32_16x16x32_fp8_fp8(wa[1][k], a2, Hacc[1][2], 0, 0, 0);
                Hacc[1][3] = __builtin_amdgcn_mfma_f32_16x16x32_fp8_fp8(wa[1][k], a3, Hacc[1][3], 0, 0, 0);
            }
            // gelu -> hw-packed fp8 u32 -> LDS (col = hid-in-chunk)
#pragma unroll
            for (int nj = 0; nj < 2; ++nj) {
                int col = w * 96 + s * 32 + nj * 16 + lq * 4;
#pragma unroll
                for (int m = 0; m < 4; ++m) {
                    f32x4 hv = Hacc[nj][m];
                    unsigned int pk = pk4_fp8(gelu_f(hv[0]), gelu_f(hv[1]),
                                              gelu_f(hv[2]), gelu_f(hv[3]));
                    *(unsigned int*)&Hs[m * 16 + lr][col] = pk;
                }
            }
        }
        __builtin_amdgcn_s_setprio(0);
        // producer barrier: LDS drained, vmcnt NOT drained
        asm volatile("s_waitcnt lgkmcnt(0)" ::: "memory");
        __builtin_amdgcn_s_barrier();
        __builtin_amdgcn_sched_barrier(0);
        // ================= GEMM2: Y += W2[:, chunk] x H(chunk), K=384 ============
        const unsigned char* q2 = w2t + ((size_t)e * DIM + w * 96 + lr) * HID + hc * 384 + lq * 8;
        __builtin_amdgcn_s_setprio(1);
#pragma unroll
        for (int k2 = 0; k2 < 12; ++k2) {
            f8x8 h0 = *(const f8x8*)&Hs[ 0 + lr][k2 * 32 + lq * 8];
            f8x8 h1 = *(const f8x8*)&Hs[16 + lr][k2 * 32 + lq * 8];
            f8x8 h2 = *(const f8x8*)&Hs[32 + lr][k2 * 32 + lq * 8];
            f8x8 h3 = *(const f8x8*)&Hs[48 + lr][k2 * 32 + lq * 8];
#pragma unroll
            for (int nj = 0; nj < 6; ++nj) {
                f8x8 wf = *(const f8x8*)(q2 + (size_t)nj * 16 * HID + k2 * 32);
                Yacc[nj][0] = __builtin_amdgcn_mfma_f32_16x16x32_fp8_fp8(wf, h0, Yacc[nj][0], 0, 0, 0);
                Yacc[nj][1] = __builtin_amdgcn_mfma_f32_16x16x32_fp8_fp8(wf, h1, Yacc[nj][1], 0, 0, 0);
                Yacc[nj][2] = __builtin_amdgcn_mfma_f32_16x16x32_fp8_fp8(wf, h2, Yacc[nj][2], 0, 0, 0);
                Yacc[nj][3] = __builtin_amdgcn_mfma_f32_16x16x32_fp8_fp8(wf, h3, Yacc[nj][3], 0, 0, 0);
            }
        }
        __builtin_amdgcn_s_setprio(0);
        // consumer barrier: Hs reads retired before next phase overwrites
        asm volatile("s_waitcnt lgkmcnt(0)" ::: "memory");
        __builtin_amdgcn_s_barrier();
        __builtin_amdgcn_sched_barrier(0);
    }

    // ---- epilogue: token = m*16+lr (col), dims = w*96 + nj*16 + lq*4 + r (rows)
    f32x4 b2v[6];
#pragma unroll
    for (int nj = 0; nj < 6; ++nj)
        b2v[nj] = *(const f32x4*)&b2[e * DIM + w * 96 + nj * 16 + lq * 4];
#pragma unroll
    for (int m = 0; m < 4; ++m) {
        int row = m * 16 + lr;
        int ent = ents[row];
        if (ent >= 0) {
            float wv = wrow[row];
            int tok = ent >> 1;
            unsigned short* yb = (ent & 1) ? y1 : y0;
#pragma unroll
            for (int nj = 0; nj < 6; ++nj) {
                u16x4 pk;
#pragma unroll
                for (int r = 0; r < 4; ++r)
                    pk[r] = f2bf((Yacc[nj][m][r] + b2v[nj][r]) * wv);
                *(u16x4*)(yb + (size_t)tok * DIM + w * 96 + nj * 16 + lq * 4) = pk;
            }
        }
    }
}

// ---------- K4: out = input + layer_scale[c] * (y0 + y1), NHWC->NCHW ----------
__global__ __launch_bounds__(256) void k_final(const float* __restrict__ input,
                                               const float* __restrict__ ls,
                                               const unsigned short* __restrict__ y0,
                                               const unsigned short* __restrict__ y1,
                                               float* __restrict__ out) {
    int b = blockIdx.x;
    int ct = b % 12;
    int hwt = (b / 12) % 32;
    int n = b / (12 * 32);
    int c0 = ct * 32, hw0 = hwt * 32;
    __shared__ float t[32][33];
    int tid = threadIdx.x;
    int t0 = n * HW + hw0;
#pragma unroll
    for (int k = 0; k < 2; ++k) {
        int idx = k * 256 + tid;
        int tl = idx >> 4, pr = idx & 15;       // 32 tokens x 16 col-pairs
        size_t o = (size_t)(t0 + tl) * DIM + c0 + pr * 2;
        unsigned int a = *(const unsigned int*)(y0 + o);
        unsigned int c = *(const unsigned int*)(y1 + o);
        t[tl][pr * 2]     = bf2f((unsigned short)a) + bf2f((unsigned short)c);
        t[tl][pr * 2 + 1] = bf2f((unsigned short)(a >> 16)) + bf2f((unsigned short)(c >> 16));
    }
    __syncthreads();
#pragma unroll
    for (int k = 0; k < 4; ++k) {
        int idx = k * 256 + tid;
        int cl = idx >> 5, j = idx & 31;
        size_t o = ((size_t)n * DIM + c0 + cl) * HW + hw0 + j;
        out[o] = input[o] + ls[c0 + cl] * t[j][cl];
    }
}

// ---------- launch ----------
extern "C" void kernel_launch(void* const* d_in, const int* in_sizes, int n_in,
                              void* d_out, int out_size, void* d_ws, size_t ws_size,
                              hipStream_t stream) {
    const float* input  = (const float*)d_in[0];
    const float* dw_w   = (const float*)d_in[1];
    const float* dw_b   = (const float*)d_in[2];
    const float* ln_g   = (const float*)d_in[3];
    const float* ln_b   = (const float*)d_in[4];
    const float* gate_w = (const float*)d_in[5];
    const float* w1     = (const float*)d_in[6];
    const float* b1     = (const float*)d_in[7];
    const float* w2     = (const float*)d_in[8];
    const float* b2     = (const float*)d_in[9];
    const float* lscale = (const float*)d_in[10];

    // ws layout (bytes)
    const size_t SZ_PLANE = (size_t)NB * DIM * HW * 4;      // 50,331,648 (xconv fp32)
    const size_t SZ_YBF   = (size_t)T_TOK * DIM * 2;        // 25,165,824 (y bf16)
    const size_t SZ_LNB   = (size_t)T_TOK * DIM;            // 12,582,912 (X fp8)
    const size_t SZ_W1    = (size_t)NE * DIM * HID;         //  4,718,592 (fp8)
    char* ws = (char*)d_ws;
    float* xconv = (float*)(ws + 0);                        // dead after k_ln_gate
    unsigned short* y0 = (unsigned short*)(ws + 0);         // overlays xconv
    unsigned short* y1 = (unsigned short*)(ws + SZ_YBF);    // still inside xconv region
    unsigned char* lnb = (unsigned char*)(ws + SZ_PLANE);
    unsigned char* w1t = (unsigned char*)(ws + SZ_PLANE + SZ_LNB);
    unsigned char* w2t = (unsigned char*)(ws + SZ_PLANE + SZ_LNB + SZ_W1);
    int*   lists  = (int*)(ws + SZ_PLANE + SZ_LNB + 2 * SZ_W1);
    float* wgt    = (float*)(ws + SZ_PLANE + SZ_LNB + 2 * SZ_W1 + 1048576);
    int*   counts = (int*)(ws + SZ_PLANE + SZ_LNB + 2 * SZ_W1 + 2 * 1048576);
    const size_t needed = SZ_PLANE + SZ_LNB + 2 * SZ_W1 + 2 * 1048576 + 256;
    if (ws_size < needed) return;

    hipMemsetAsync(counts, 0, 32, stream);
    k_transpose8<<<8 * 12 * 48, 256, 0, stream>>>(w1, w1t, DIM, HID);
    k_transpose8<<<8 * 48 * 12, 256, 0, stream>>>(w2, w2t, HID, DIM);
    k_conv<<<NB * DIM, 256, 0, stream>>>(input, dw_w, dw_b, xconv);
    k_ln_gate<<<T_TOK / 32, 256, 0, stream>>>(xconv, ln_g, ln_b, gate_w, lnb, lists, wgt, counts);
    k_moe<<<NE * 512, 256, 0, stream>>>(lnb, w1t, w2t, b1, b2, lists, wgt, counts, y0, y1);
    k_final<<<NB * 32 * 12, 256, 0, stream>>>(input, lscale, y0, y1, (float*)d_out);
}